// Round 16
// baseline (148.246 us; speedup 1.0000x reference)
//
#include <hip/hip_runtime.h>
#include <hip/hip_bf16.h>
#include <stdint.h>

#define B_DIM   4096
#define IN_DIM  512
#define OUT_DIM 512
#define M_DIM   16
#define K_DIM   (IN_DIM * M_DIM)     // 8192
#define MN      (B_DIM * OUT_DIM)    // 2097152

typedef unsigned short ushort_t;
typedef __attribute__((ext_vector_type(8))) __bf16 bf16x8;
typedef __attribute__((ext_vector_type(2))) __bf16 bf16x2;
typedef __attribute__((ext_vector_type(4))) float  f32x4;

__device__ __forceinline__ ushort_t f2bf(float f) {
  union { float f; uint32_t u; } v; v.f = f;
  uint32_t u = v.u + 0x7fffu + ((v.u >> 16) & 1u);   // RNE
  return (ushort_t)(u >> 16);
}

__device__ __forceinline__ uint32_t pkbf(float lo, float hi) {
  union { bf16x2 h; uint32_t u; } v;
  v.h[0] = (__bf16)lo; v.h[1] = (__bf16)hi;
  return v.u;
}

__device__ __forceinline__ float rfl(float f) {
  union { float f; int i; } v; v.f = f;
  v.i = __builtin_amdgcn_readfirstlane(v.i);
  return v.f;
}

// ---------- phase 1: coeffs fp32 -> bf16 (layout [OUT][IN][M] == B^T [N][K]) ----------
#define CONV_N4 (OUT_DIM * K_DIM / 4)
__global__ __launch_bounds__(256) void convert_coeffs_kernel(
    const float* __restrict__ src, ushort_t* __restrict__ dst) {
  int i = blockIdx.x * 256 + threadIdx.x;
  float4 v = ((const float4*)src)[i];
  ushort4 o;
  o.x = f2bf(v.x); o.y = f2bf(v.y); o.z = f2bf(v.z); o.w = f2bf(v.w);
  ((ushort4*)dst)[i] = o;
}

// ---------- phase 2: FUSED basis+GEMM, 8-PHASE interleave (T3+T4 port) ----------
// Rationale: r15's gemm = 573 TF = exactly the documented 2-barrier/K-step
// structure ceiling (m230/m233: 600-680 TF); every single-lever fix was null,
// matching m233 ("removing ds_read or one barrier alone doesn't help"). The
// evidenced fix is the m201 8-phase schedule: fine ds_read/stage/MFMA
// interleave + counted vmcnt(4) at 2 of 8 phases, never 0 in the main loop.
#define BM 128
#define BN 512
#define BK 32                 // = 2 input-columns x 16 m; iter = 2 K-steps (K=64)
#define SPLITK 8
#define KC (K_DIM / SPLITK)   // 1024
#define NITER (KC / BK)       // 32 K-steps = 16 iters
#define XCOLS (KC / M_DIM)    // 64 x-columns per block
#define XPAD  129

#define GLD16(g, l) \
  __builtin_amdgcn_global_load_lds((const __attribute__((address_space(1))) void*)(g), \
                                   (__attribute__((address_space(3))) void*)(l), 16, 0, 0)

#define BARX()   asm volatile("s_barrier" ::: "memory")
#define LGKM0()  asm volatile("s_waitcnt lgkmcnt(0)" ::: "memory")
#define EPI_L()  asm volatile("s_waitcnt lgkmcnt(0)\n\ts_barrier" ::: "memory")
#define EPI_V4() asm volatile("s_waitcnt vmcnt(4) lgkmcnt(0)\n\ts_barrier" ::: "memory")
#define EPI_V0() asm volatile("s_waitcnt vmcnt(0) lgkmcnt(0)\n\ts_barrier" ::: "memory")

template <int ATOMIC>
__global__ __launch_bounds__(512, 2) void gemm_kernel(
    const float* __restrict__ x,      // [B_DIM][IN_DIM] fp32
    const ushort_t* __restrict__ Bt,  // coeffs bf16 [OUT_DIM][K_DIM]
    const float* __restrict__ bc,     // [16][8]
    float* __restrict__ P) {          // permuted partials [SPLITK][...] or out
  // LDS: As TRIBUF 24K + Bs TRIBUF 96K + Xs 32.25K = 152.25 KiB (1 block/CU)
  // Slot lifecycle (slot = step % 3 for BOTH As and Bs):
  //   iter i computes steps (2i, 2i+1) from slots (2i%3, (2i+1)%3);
  //   produces/stages steps (2i+2 -> p0-p3, 2i+3 -> p4-p7) into the remaining
  //   slot and the just-freed sA slot — always barrier-separated from reads.
  __shared__ __align__(16) ushort_t As[3][BM * BK];
  __shared__ __align__(16) ushort_t Bs[3][BN * BK];
  __shared__ __align__(16) float    Xs[XCOLS * XPAD];
  const int tid  = threadIdx.x;
  const int wave = tid >> 6;
  const int lane = tid & 63;
  const int wgid = blockIdx.x;
  const int ks = wgid & 7, bm = wgid >> 3;   // same-ks blocks -> same XCD, B-slice L2-hot

  // ---- x-tile staging (one-time): coalesced float4 loads -> transposed LDS ----
  {
    const int r = tid >> 2, q = tid & 3;
    const float4* xrow = (const float4*)(x + (size_t)(bm * BM + r) * IN_DIM + ks * XCOLS);
    #pragma unroll
    for (int j = 0; j < 4; ++j) {
      float4 v = xrow[q * 4 + j];
      Xs[(q * 16 + j * 4 + 0) * XPAD + r] = v.x;
      Xs[(q * 16 + j * 4 + 1) * XPAD + r] = v.y;
      Xs[(q * 16 + j * 4 + 2) * XPAD + r] = v.z;
      Xs[(q * 16 + j * 4 + 3) * XPAD + r] = v.w;
    }
  }

  // ---- B staging addresses: linear LDS dest, pre-swizzled global source ----
  const int srow = wave * 16 + (lane >> 2);
  const int scol = (((lane & 3) ^ ((lane >> 3) & 3)) * 8);
  const ushort_t* Bg0 = Bt + (size_t)srow * K_DIM + ks * KC + scol;
  const ushort_t* Bg1 = Bg0 + (size_t)128 * K_DIM;
  const ushort_t* Bg2 = Bg0 + (size_t)256 * K_DIM;
  const ushort_t* Bg3 = Bg0 + (size_t)384 * K_DIM;
  const int bofs0 = (wave * 16) * BK;
  const int bofs1 = (128 + wave * 16) * BK;
  const int bofs2 = (256 + wave * 16) * BK;
  const int bofs3 = (384 + wave * 16) * BK;

  // ---- basis production mapping (r9): thread -> (row, il, m-half) ----
  const int half = wave & 1;
  const int arow = (wave >> 1) * 32 + (lane >> 1);
  const int il   = lane & 1;
  const int aslot = ((il * 2 + half) ^ ((lane >> 2) & 3));
  const int awe   = arow * BK + aslot * 8;
  const int xbase = il * XPAD + arow;

  const float LOG2E = 1.44269504088896340736f;
  const float LN2   = 0.69314718055994530942f;
  float c1[8], c2[8], c3[8], c4[8], c5[8], c6[8], c7[8], c8[8];
  {
    const float* bch = bc + half * 64;
    #pragma unroll
    for (int m = 0; m < 8; ++m) {
      c1[m] = rfl(rfl(bch[m*8+0]) * LN2); c2[m] = rfl(rfl(bch[m*8+1]) * LN2);
      c3[m] = rfl(bch[m*8+2]); c4[m] = rfl(bch[m*8+3]);
      c5[m] = rfl(bch[m*8+4]); c6[m] = rfl(bch[m*8+5]);
      c7[m] = rfl(bch[m*8+6]); c8[m] = rfl(bch[m*8+7]);
    }
  }

  // 4-m BASIS slice (half a step's production; two slices fill one 16B slot)
#define BASIS4(ab, t_, mi0) do { \
    float xv = Xs[xbase + 2 * XPAD * (t_)]; \
    float xl2 = xv * LOG2E; \
    float x2 = xv * xv, x3 = x2 * xv, x4 = x2 * x2; \
    float ym[4]; \
    _Pragma("unroll") \
    for (int mi = 0; mi < 4; ++mi) { int mm = (mi0) + mi; \
      float e     = __builtin_amdgcn_exp2f(c3[mm] * xl2); \
      float inner = e - 1.0f; \
      float p     = __builtin_amdgcn_exp2f(c4[mm] * __builtin_amdgcn_logf(inner)); \
      float L1    = __builtin_amdgcn_logf(1.0f + p); \
      float vv    = __builtin_amdgcn_logf(1.0f + c2[mm] * L1); \
      ym[mi] = c1[mm] * vv + c5[mm] * xv + c6[mm] * x2 + c7[mm] * x3 + c8[mm] * x4; \
    } \
    *(uint2*)(&As[ab][awe + (mi0)]) = make_uint2(pkbf(ym[0], ym[1]), pkbf(ym[2], ym[3])); \
  } while (0)

  // ---- MFMA geometry: 8 waves as 2x4 grid of 64x128 wave-tiles ----
  const int wr = wave >> 2, wc = wave & 3;
  const int fm = lane & 15;
  const int fkswz = (((lane >> 4) ^ ((lane >> 1) & 3)) << 3);

  f32x4 acc[4][8] = {};

#define LD_AF(s) do { _Pragma("unroll") \
    for (int t2 = 0; t2 < 4; ++t2) \
      af[t2] = *(const bf16x8*)&As[s][(wr * 64 + t2 * 16 + fm) * BK + fkswz]; } while (0)
#define LD_B2(s, q) do { \
    b0 = *(const bf16x8*)&Bs[s][(wc * 128 + (2*(q))    * 16 + fm) * BK + fkswz]; \
    b1 = *(const bf16x8*)&Bs[s][(wc * 128 + (2*(q)+1)  * 16 + fm) * BK + fkswz]; } while (0)
#define MF8(q) do { __builtin_amdgcn_s_setprio(1); \
    _Pragma("unroll") \
    for (int mt = 0; mt < 4; ++mt) { \
      acc[mt][2*(q)]   = __builtin_amdgcn_mfma_f32_16x16x32_bf16(af[mt], b0, acc[mt][2*(q)],   0, 0, 0); \
      acc[mt][2*(q)+1] = __builtin_amdgcn_mfma_f32_16x16x32_bf16(af[mt], b1, acc[mt][2*(q)+1], 0, 0, 0); \
    } __builtin_amdgcn_s_setprio(0); } while (0)

  // one iter = 2 K-steps, 8 phases. vmcnt ledger (per wave, 1 gld/phase):
  //   p3-epi: outstanding = batch(2i+1)[4] + batch(2i+2)[4] = 8 -> vmcnt(4)
  //           retires 2i+1 (read at p4). p7-epi: retires 2i+2 (read next p0).
#define ITER(sA, sB, sP, sQ, tp_) do { \
    bf16x8 af[4], b0, b1; \
    /* p0 */ LD_AF(sA); LD_B2(sA, 0); GLD16(Bg0, &Bs[sP][bofs0]); \
    BARX(); LGKM0(); MF8(0); EPI_L(); \
    /* p1 */ LD_B2(sA, 1); GLD16(Bg1, &Bs[sP][bofs1]); \
    BARX(); LGKM0(); MF8(1); BASIS4(sP, (tp_), 0); EPI_L(); \
    /* p2 */ LD_B2(sA, 2); GLD16(Bg2, &Bs[sP][bofs2]); \
    BARX(); LGKM0(); MF8(2); BASIS4(sP, (tp_), 4); EPI_L(); \
    /* p3 */ LD_B2(sA, 3); GLD16(Bg3, &Bs[sP][bofs3]); \
    Bg0 += BK; Bg1 += BK; Bg2 += BK; Bg3 += BK; \
    BARX(); LGKM0(); MF8(3); EPI_V4(); \
    /* p4 */ LD_AF(sB); LD_B2(sB, 0); GLD16(Bg0, &Bs[sQ][bofs0]); \
    BARX(); LGKM0(); MF8(0); EPI_L(); \
    /* p5 */ LD_B2(sB, 1); GLD16(Bg1, &Bs[sQ][bofs1]); \
    BARX(); LGKM0(); MF8(1); BASIS4(sQ, (tp_) + 1, 0); EPI_L(); \
    /* p6 */ LD_B2(sB, 2); GLD16(Bg2, &Bs[sQ][bofs2]); \
    BARX(); LGKM0(); MF8(2); BASIS4(sQ, (tp_) + 1, 4); EPI_L(); \
    /* p7 */ LD_B2(sB, 3); GLD16(Bg3, &Bs[sQ][bofs3]); \
    Bg0 += BK; Bg1 += BK; Bg2 += BK; Bg3 += BK; \
    BARX(); LGKM0(); MF8(3); EPI_V4(); \
  } while (0)

  // ---- prologue: stage batches 0,1; full drain; produce As steps 0,1 ----
  GLD16(Bg0, &Bs[0][bofs0]); GLD16(Bg1, &Bs[0][bofs1]);
  GLD16(Bg2, &Bs[0][bofs2]); GLD16(Bg3, &Bs[0][bofs3]);
  Bg0 += BK; Bg1 += BK; Bg2 += BK; Bg3 += BK;
  GLD16(Bg0, &Bs[1][bofs0]); GLD16(Bg1, &Bs[1][bofs1]);
  GLD16(Bg2, &Bs[1][bofs2]); GLD16(Bg3, &Bs[1][bofs3]);
  Bg0 += BK; Bg1 += BK; Bg2 += BK; Bg3 += BK;
  __syncthreads();              // full drain: Xs + batches 0,1 resident
  BASIS4(0, 0, 0); BASIS4(0, 0, 4);   // step 0 -> As[0]
  BASIS4(1, 1, 0); BASIS4(1, 1, 4);   // step 1 -> As[1]
  EPI_L();                      // As[0..1] visible

  // ---- main loop: iters 0..14 (steps 0..29); slot pattern period = 3 iters ----
  for (int ii = 0, tp = 2; ii < 5; ++ii, tp += 6) {
    ITER(0, 1, 2, 0, tp);       // i%3==0
    ITER(2, 0, 1, 2, tp + 2);   // i%3==1
    ITER(1, 2, 0, 1, tp + 4);   // i%3==2
  }

  // ---- last iter (steps 30,31): no staging/production; p3 drains batch 31 ----
  {
    bf16x8 af[4], b0, b1;
    LD_AF(0); LD_B2(0, 0); BARX(); LGKM0(); MF8(0); EPI_L();
    LD_B2(0, 1);           BARX(); LGKM0(); MF8(1); EPI_L();
    LD_B2(0, 2);           BARX(); LGKM0(); MF8(2); EPI_L();
    LD_B2(0, 3);           BARX(); LGKM0(); MF8(3); EPI_V0();
    LD_AF(1); LD_B2(1, 0); BARX(); LGKM0(); MF8(0); EPI_L();
    LD_B2(1, 1);           BARX(); LGKM0(); MF8(1); EPI_L();
    LD_B2(1, 2);           BARX(); LGKM0(); MF8(2); EPI_L();
    LD_B2(1, 3);           BARX(); LGKM0(); MF8(3);
  }

  // ---- C-write ----
  if (ATOMIC) {
    const int colb = wc * 128 + fm;
    const int rowb = bm * BM + wr * 64 + (lane >> 4) * 4;
    #pragma unroll
    for (int mt = 0; mt < 4; ++mt)
      #pragma unroll
      for (int nt = 0; nt < 8; ++nt)
        #pragma unroll
        for (int j = 0; j < 4; ++j)
          atomicAdd(P + (size_t)(rowb + mt * 16 + j) * OUT_DIM + (colb + nt * 16),
                    acc[mt][nt][j]);
  } else {
    // lane-contiguous permuted partial store (r15): 1KB/wave-instr coalesced
    float* dst = P + (size_t)ks * MN + (size_t)bm * (BM * BN)
                   + wave * 8192 + lane * 4;
    #pragma unroll
    for (int mt = 0; mt < 4; ++mt)
      #pragma unroll
      for (int nt = 0; nt < 8; ++nt)
        *(f32x4*)(dst + (mt * 8 + nt) * 256) = acc[mt][nt];
  }
#undef BASIS4
#undef LD_AF
#undef LD_B2
#undef MF8
#undef ITER
}

// ---------- phase 3: reduce permuted split-K partials -> row-major out ----------
__global__ __launch_bounds__(256) void reduce_kernel(
    const float* __restrict__ P, float* __restrict__ out) {
  int i = blockIdx.x * 256 + threadIdx.x;
  const float4* p = (const float4*)P;
  float4 r = p[i];
  #pragma unroll
  for (int s = 1; s < SPLITK; ++s) {
    float4 v = p[i + (size_t)s * (MN / 4)];
    r.x += v.x; r.y += v.y; r.z += v.z; r.w += v.w;
  }
  // decode permuted slot: i = bm*16384 + wave*2048 + (mt*8+nt)*64 + lane
  int bm   = i >> 14;
  int rem  = i & 16383;
  int wv   = rem >> 11;
  int rem2 = rem & 2047;
  int mtnt = rem2 >> 6;
  int lane = rem2 & 63;
  int mt = mtnt >> 3, nt = mtnt & 7;
  int wr = wv >> 2,  wc = wv & 3;
  int row = bm * BM + wr * 64 + mt * 16 + (lane >> 4) * 4;
  int col = wc * 128 + nt * 16 + (lane & 15);
  float* o = out + (size_t)row * OUT_DIM + col;
  o[0 * OUT_DIM] = r.x;
  o[1 * OUT_DIM] = r.y;
  o[2 * OUT_DIM] = r.z;
  o[3 * OUT_DIM] = r.w;
}

extern "C" void kernel_launch(void* const* d_in, const int* in_sizes, int n_in,
                              void* d_out, int out_size, void* d_ws, size_t ws_size,
                              hipStream_t stream) {
  const float* x      = (const float*)d_in[0];   // [4096][512]
  const float* coeffs = (const float*)d_in[1];   // [512][512][16]
  const float* b_coef = (const float*)d_in[2];   // [16][8]
  float* out = (float*)d_out;
  char*  ws  = (char*)d_ws;

  const size_t COEF_BYTES = (size_t)OUT_DIM * K_DIM * 2;   // 8 MiB
  ushort_t* coefb = (ushort_t*)ws;
  float* partials = (float*)(ws + COEF_BYTES);
  const size_t FULL = COEF_BYTES + (size_t)SPLITK * MN * 4;  // 72 MiB
  const bool use_atomic = (ws_size < FULL);   // deterministic per-session branch

  convert_coeffs_kernel<<<CONV_N4 / 256, 256, 0, stream>>>(coeffs, coefb);

  const int nblk = (B_DIM / BM) * SPLITK;   // 32 x 8 = 256 blocks, 1/CU
  if (use_atomic) {
    hipMemsetAsync(d_out, 0, (size_t)MN * 4, stream);
    gemm_kernel<1><<<nblk, 512, 0, stream>>>(x, coefb, b_coef, out);
  } else {
    gemm_kernel<0><<<nblk, 512, 0, stream>>>(x, coefb, b_coef, partials);
    reduce_kernel<<<MN / 4 / 256, 256, 0, stream>>>(partials, out);
  }
}